// Round 2
// baseline (363.944 us; speedup 1.0000x reference)
//
#include <hip/hip_runtime.h>
#include <hip/hip_bf16.h>
#include <stdint.h>

// Problem constants
#define BT    (256*2048)      // 524288 tokens
#define DIN   25
#define DP    128
#define MTILE 128             // tokens per block (4 waves x 32 tokens)
#define NBLK  (BT/MTILE)      // 4096 blocks
#define HSTR  136             // h row stride in bf16 (pad 128->136)
#define WREG  (32*HSTR*2)     // 8704 B per-wave region
#define XOFF  4608            // x stage at TOP of wave region (4608+4096 = 8704)
                              // -> disjoint from tile-0 h rows (bytes 0..4334): no
                              //    write-under-read hazard even if compiler sinks loads
#define SM_BYTES (4*WREG)     // 34816 B -> 4 blocks/CU

typedef __attribute__((ext_vector_type(8))) __bf16          bf16x8;
typedef __attribute__((ext_vector_type(8))) unsigned short  u16x8;
typedef __attribute__((ext_vector_type(4))) float           f32x4;

__device__ __forceinline__ unsigned short f2bf(float f) {
  unsigned int u = __float_as_uint(f);
  u += 0x7fffu + ((u >> 16) & 1u);          // round-to-nearest-even
  return (unsigned short)(u >> 16);
}

// exact-erf GELU via Abramowitz&Stegun 7.1.26 (|eps|<=1.5e-7), ~15 VALU ops
__device__ __forceinline__ float gelu_exact(float x) {
  float z  = 0.70710678118654752f * x;
  float az = __builtin_fabsf(z);
  float t  = __builtin_amdgcn_rcpf(1.0f + 0.3275911f * az);
  float p  = t*(0.254829592f + t*(-0.284496736f + t*(1.421413741f +
             t*(-1.453152027f + t*1.061405429f))));
  float e  = __expf(-z*z);                  // v_exp_f32 path
  float erf_az = 1.0f - p*e;
  float erf_z  = (x < 0.f) ? -erf_az : erf_az;
  return 0.5f * x * (1.0f + erf_z);
}

__device__ __forceinline__ void async16(void* lds, const void* g) {
  __builtin_amdgcn_global_load_lds(
      (const __attribute__((address_space(1))) unsigned int*)g,
      (__attribute__((address_space(3)))       unsigned int*)lds, 16, 0, 0);
}

// ---------------------------------------------------------------------------
// Prep: pack w1 (K padded 25->32, zero fill) and w2 into bf16 MFMA B-fragment
// lane order. B-frag (16x16x32): elem(lane,j) = B[k = (lane>>4)*8 + j][n = nt*16 + (lane&15)]
// ws layout: [w1 frags nt=0..7][w2 frags f = nt*4 + ks]  (each frag 512 bf16 = 1 KB)
// ---------------------------------------------------------------------------
__global__ void prep_kernel(const float* __restrict__ w1, const float* __restrict__ w2,
                            unsigned short* __restrict__ wf) {
  int idx = blockIdx.x * 256 + threadIdx.x;
  if (idx >= 40 * 512) return;
  int f = idx >> 9, r = idx & 511, l = r >> 3, j = r & 7;
  float val;
  if (f < 8) {                       // w1 frag, nt = f
    int k = (l >> 4) * 8 + j;
    int n = f * 16 + (l & 15);
    val = (k < DIN) ? w1[k * DP + n] : 0.f;
  } else {                           // w2 frag
    int g = f - 8, nt = g >> 2, ks = g & 3;
    int k = ks * 32 + (l >> 4) * 8 + j;
    int n = nt * 16 + (l & 15);
    val = w2[k * DP + n];
  }
  wf[idx] = f2bf(val);
}

// ---------------------------------------------------------------------------
// Fused LN -> mm1(+b1,GELU) -> mm2(+b2), ZERO block barriers.
// Each wave owns 32 tokens end-to-end:
//   stage x (global_load_lds, top of wave LDS slot) -> per-lane LN (shfl_xor
//   across quads, fused into A-frag build) -> mm1 -> gelu -> h (bottom of the
//   same slot) -> wave-local lgkmcnt fence -> mm2 (row-split, w2 from L1/L2).
// ---------------------------------------------------------------------------
__global__ __launch_bounds__(256, 4) void fused_kernel(
    const float* __restrict__ x,   const float* __restrict__ gam,
    const float* __restrict__ bet, const float* __restrict__ b1,
    const float* __restrict__ b2,  const unsigned short* __restrict__ wfr,
    float* __restrict__ out) {
  __shared__ __align__(16) unsigned char smem[SM_BYTES];
  const int tid  = threadIdx.x;
  const int lane = tid & 63, w = tid >> 6;
  const int quad = lane >> 4, l15 = lane & 15;
  const int kbase = quad * 8;
  const long long rowW = (long long)blockIdx.x * MTILE + w * 32;  // wave's first token
  unsigned char* wbase = smem + w * WREG;
  const unsigned char* wfb = (const unsigned char*)wfr;

  // ---- stage this wave's 32 rows of x (800 floats; pad to 1024) into LDS ----
  {
    const long long xoff0 = rowW * (DIN * 4);
    const long long xmax  = (long long)BT * DIN * 4 - 16;   // clamp pad reads in-bounds
#pragma unroll
    for (int i = 0; i < 4; i++) {
      long long off = xoff0 + (long long)(i * 64 + lane) * 16;
      if (off > xmax) off = xmax;
      async16(wbase + XOFF + i * 1024 + lane * 16, (const unsigned char*)x + off);
    }
  }

  // ---- per-lane small preloads + w1 frags (issued before the vmcnt drain) ----
  float gk[8], bk[8];
#pragma unroll
  for (int j = 0; j < 8; j++) {
    int k = kbase + j;
    bool v = (k < DIN);
    gk[j] = v ? gam[k] : 0.f;
    bk[j] = v ? bet[k] : 0.f;
  }
  bf16x8 wb1[8];
#pragma unroll
  for (int nt = 0; nt < 8; nt++)
    wb1[nt] = *(const bf16x8*)(wfb + nt * 1024 + lane * 16);

  // wait for this wave's global_load_lds (no block barrier: purely wave-local)
  asm volatile("s_waitcnt vmcnt(0)" ::: "memory");
  __builtin_amdgcn_sched_barrier(0);

  // ---- LN fused into A-frag build (two-pass variance, all in registers) ----
  const float* xs = (const float*)(wbase + XOFF);
  bf16x8 afrag[2];
#pragma unroll
  for (int t = 0; t < 2; t++) {
    float xv[8];
    float s = 0.f;
#pragma unroll
    for (int j = 0; j < 8; j++) {
      int k = kbase + j;
      float v = 0.f;
      if (k < DIN) v = xs[(t * 16 + l15) * DIN + k];
      xv[j] = v;
      s += v;
    }
    // row sum lives across lanes {l15, l15+16, l15+32, l15+48}
    s += __shfl_xor(s, 16);  s += __shfl_xor(s, 32);
    float mu = s * (1.f / DIN);
    float vv = 0.f;
#pragma unroll
    for (int j = 0; j < 8; j++) {
      int k = kbase + j;
      float d = (k < DIN) ? (xv[j] - mu) : 0.f;
      vv += d * d;
    }
    vv += __shfl_xor(vv, 16); vv += __shfl_xor(vv, 32);
    float inv = rsqrtf(vv * (1.f / DIN) + 1e-5f);
    u16x8 pk;
#pragma unroll
    for (int j = 0; j < 8; j++)
      pk[j] = f2bf((xv[j] - mu) * inv * gk[j] + bk[j]);   // gk=bk=0 on pad -> 0
    afrag[t] = __builtin_bit_cast(bf16x8, pk);
  }

  // ---- mm1 + bias + gelu -> per-wave h scratch [32][HSTR] bf16 (bottom of slot) ----
  float b1v[8];
#pragma unroll
  for (int nt = 0; nt < 8; nt++) b1v[nt] = b1[nt * 16 + l15];

  unsigned short* hb = (unsigned short*)wbase;
  const f32x4 zf = {0.f, 0.f, 0.f, 0.f};
#pragma unroll
  for (int t = 0; t < 2; t++) {
    f32x4 acc[8];
#pragma unroll
    for (int nt = 0; nt < 8; nt++)
      acc[nt] = __builtin_amdgcn_mfma_f32_16x16x32_bf16(afrag[t], wb1[nt], zf, 0, 0, 0);
#pragma unroll
    for (int nt = 0; nt < 8; nt++) {
      float bias = b1v[nt];
      int col = nt * 16 + l15;
#pragma unroll
      for (int r = 0; r < 4; r++) {
        int row = t * 16 + quad * 4 + r;
        hb[row * HSTR + col] = f2bf(gelu_exact(acc[nt][r] + bias));
      }
    }
  }

  // ---- wave-local fence: h ds_writes complete + compiler may not hoist the
  //      af ds_reads (different TBAA type!) above the h stores ----
  asm volatile("s_waitcnt lgkmcnt(0)" ::: "memory");
  __builtin_amdgcn_sched_barrier(0);

  // ---- mm2: out = h @ w2 + b2, row-split (wave keeps its own 32 rows) ----
  bf16x8 af[2][4];
#pragma unroll
  for (int t = 0; t < 2; t++)
#pragma unroll
    for (int ks = 0; ks < 4; ks++)
      af[t][ks] = *(const bf16x8*)((const unsigned char*)hb +
                    (t * 16 + l15) * (HSTR * 2) + ks * 64 + quad * 16);

  float b2v[8];
#pragma unroll
  for (int nt = 0; nt < 8; nt++) b2v[nt] = b2[nt * 16 + l15];

  float* orow = out + rowW * DP;
#pragma unroll
  for (int nt = 0; nt < 8; nt++) {
    bf16x8 wq[4];                              // stream w2 frags: L1/L2-resident
#pragma unroll
    for (int ks = 0; ks < 4; ks++)
      wq[ks] = *(const bf16x8*)(wfb + 8192 + (nt * 4 + ks) * 1024 + lane * 16);
    f32x4 a0 = zf, a1 = zf;
#pragma unroll
    for (int ks = 0; ks < 4; ks++) {
      a0 = __builtin_amdgcn_mfma_f32_16x16x32_bf16(af[0][ks], wq[ks], a0, 0, 0, 0);
      a1 = __builtin_amdgcn_mfma_f32_16x16x32_bf16(af[1][ks], wq[ks], a1, 0, 0, 0);
    }
    int col = nt * 16 + l15;
    float bias = b2v[nt];
#pragma unroll
    for (int r = 0; r < 4; r++) {
      int rr = quad * 4 + r;
      orow[(long long)(rr)      * DP + col] = a0[r] + bias;
      orow[(long long)(rr + 16) * DP + col] = a1[r] + bias;
    }
  }
}

extern "C" void kernel_launch(void* const* d_in, const int* in_sizes, int n_in,
                              void* d_out, int out_size, void* d_ws, size_t ws_size,
                              hipStream_t stream) {
  const float* x   = (const float*)d_in[0];
  const float* gam = (const float*)d_in[1];
  const float* bet = (const float*)d_in[2];
  const float* w1  = (const float*)d_in[3];
  const float* b1  = (const float*)d_in[4];
  const float* w2  = (const float*)d_in[5];
  const float* b2  = (const float*)d_in[6];
  float* out = (float*)d_out;
  unsigned short* wf = (unsigned short*)d_ws;   // 40KB of packed bf16 weight frags

  prep_kernel<<<80, 256, 0, stream>>>(w1, w2, wf);
  fused_kernel<<<NBLK, 256, 0, stream>>>(x, gam, bet, b1, b2, wf, out);
}

// Round 3
// 345.064 us; speedup vs baseline: 1.0547x; 1.0547x over previous
//
#include <hip/hip_runtime.h>
#include <hip/hip_bf16.h>
#include <stdint.h>

// Problem constants
#define BT    (256*2048)      // 524288 tokens
#define DIN   25
#define DP    128
#define MTILE 128             // tokens per block (4 waves x 32 tokens for LN/mm1)
#define NBLK  (BT/MTILE)      // 4096 blocks
#define HSTR  136             // h row stride in bf16 (pad 128->136: conflict-free frag reads)
#define WREG  (32*HSTR*2)     // 8704 B per-wave h row-band
#define XOFF  4608            // x stage at top of wave band (4608+4096=8704); tile-0 h
                              // writes end at byte 4335 -> disjoint even under reordering
#define SM_BYTES (4*WREG)     // 34816 B -> 4 blocks/CU

typedef __attribute__((ext_vector_type(8))) __bf16          bf16x8;
typedef __attribute__((ext_vector_type(4))) float           f32x4;

__device__ __forceinline__ unsigned short f2bf(float f) {
  unsigned int u = __float_as_uint(f);
  u += 0x7fffu + ((u >> 16) & 1u);          // round-to-nearest-even
  return (unsigned short)(u >> 16);
}

// exact-erf GELU via Abramowitz&Stegun 7.1.26 (|eps|<=1.5e-7), ~15 VALU ops
__device__ __forceinline__ float gelu_exact(float x) {
  float z  = 0.70710678118654752f * x;
  float az = __builtin_fabsf(z);
  float t  = __builtin_amdgcn_rcpf(1.0f + 0.3275911f * az);
  float p  = t*(0.254829592f + t*(-0.284496736f + t*(1.421413741f +
             t*(-1.453152027f + t*1.061405429f))));
  float e  = __expf(-z*z);                  // v_exp_f32 path
  float erf_az = 1.0f - p*e;
  float erf_z  = (x < 0.f) ? -erf_az : erf_az;
  return 0.5f * x * (1.0f + erf_z);
}

__device__ __forceinline__ void async16(void* lds, const void* g) {
  __builtin_amdgcn_global_load_lds(
      (const __attribute__((address_space(1))) unsigned int*)g,
      (__attribute__((address_space(3)))       unsigned int*)lds, 16, 0, 0);
}

// ---------------------------------------------------------------------------
// Prep: pack w1 (K padded 25->32, zero fill) and w2 into bf16 MFMA B-fragment
// lane order. B-frag (16x16x32): elem(lane,j) = B[k = (lane>>4)*8 + j][n = nt*16 + (lane&15)]
// ws layout: [w1 frags nt=0..7][w2 frags f = nt*4 + ks]  (each frag 512 bf16 = 1 KB)
// ---------------------------------------------------------------------------
__global__ void prep_kernel(const float* __restrict__ w1, const float* __restrict__ w2,
                            unsigned short* __restrict__ wf) {
  int idx = blockIdx.x * 256 + threadIdx.x;
  if (idx >= 40 * 512) return;
  int f = idx >> 9, r = idx & 511, l = r >> 3, j = r & 7;
  float val;
  if (f < 8) {                       // w1 frag, nt = f
    int k = (l >> 4) * 8 + j;
    int n = f * 16 + (l & 15);
    val = (k < DIN) ? w1[k * DP + n] : 0.f;
  } else {                           // w2 frag
    int g = f - 8, nt = g >> 2, ks = g & 3;
    int k = ks * 32 + (l >> 4) * 8 + j;
    int n = nt * 16 + (l & 15);
    val = w2[k * DP + n];
  }
  wf[idx] = f2bf(val);
}

// ---------------------------------------------------------------------------
// Fused LN -> mm1(+b1,GELU) -> mm2(+b2), ONE block barrier.
//   per wave: stage 32 rows of x (async to top of own h band) -> fused LN
//   (shfl across quads) -> mm1 (wb1 in regs) -> issue wb2 preload -> gelu
//   epilogue -> h in LDS -> __syncthreads -> mm2 col-split (wb2 in regs,
//   af from LDS, reused across 8 row-tiles) -> out.
// ---------------------------------------------------------------------------
__global__ __launch_bounds__(256, 4) void fused_kernel(
    const float* __restrict__ x,   const float* __restrict__ gam,
    const float* __restrict__ bet, const float* __restrict__ b1,
    const float* __restrict__ b2,  const unsigned short* __restrict__ wfr,
    float* __restrict__ out) {
  __shared__ __align__(16) unsigned char smem[SM_BYTES];
  const int tid  = threadIdx.x;
  const int lane = tid & 63, w = tid >> 6;
  const int quad = lane >> 4, l15 = lane & 15;
  const int kbase = quad * 8;
  const long long rowW = (long long)blockIdx.x * MTILE + w * 32;  // wave's first token
  unsigned char* wband = smem + w * WREG;
  const unsigned char* wfb = (const unsigned char*)wfr;

  // ---- stage this wave's 32 rows of x (800 floats; pad to 1024) into LDS ----
  {
    const long long xoff0 = rowW * (DIN * 4);
    const long long xmax  = (long long)BT * DIN * 4 - 16;   // clamp pad reads in-bounds
#pragma unroll
    for (int i = 0; i < 4; i++) {
      long long off = xoff0 + (long long)(i * 64 + lane) * 16;
      if (off > xmax) off = xmax;
      async16(wband + XOFF + i * 1024 + lane * 16, (const unsigned char*)x + off);
    }
  }

  // ---- per-lane small preloads + w1 frags (overlap the HBM x fetch) ----
  float gk[8], bk[8];
#pragma unroll
  for (int j = 0; j < 8; j++) {
    int k = kbase + j;
    bool v = (k < DIN);
    gk[j] = v ? gam[k] : 0.f;
    bk[j] = v ? bet[k] : 0.f;
  }
  bf16x8 wb1[8];
#pragma unroll
  for (int nt = 0; nt < 8; nt++)
    wb1[nt] = *(const bf16x8*)(wfb + nt * 1024 + lane * 16);
  float b1v[8];
#pragma unroll
  for (int nt = 0; nt < 8; nt++) b1v[nt] = b1[nt * 16 + l15];

  // wait for this wave's global_load_lds (wave-local; no block barrier)
  asm volatile("s_waitcnt vmcnt(0)" ::: "memory");
  __builtin_amdgcn_sched_barrier(0);

  // ---- LN fused into A-frag build (two-pass variance, all in registers) ----
  const float* xs = (const float*)(wband + XOFF);
  bf16x8 afrag[2];
#pragma unroll
  for (int t = 0; t < 2; t++) {
    float xv[8];
    float s = 0.f;
#pragma unroll
    for (int j = 0; j < 8; j++) {
      int k = kbase + j;
      float v = 0.f;
      if (k < DIN) v = xs[(t * 16 + l15) * DIN + k];
      xv[j] = v;
      s += v;
    }
    // row sum lives across lanes {l15, l15+16, l15+32, l15+48}
    s += __shfl_xor(s, 16);  s += __shfl_xor(s, 32);
    float mu = s * (1.f / DIN);
    float vv = 0.f;
#pragma unroll
    for (int j = 0; j < 8; j++) {
      int k = kbase + j;
      float d = (k < DIN) ? (xv[j] - mu) : 0.f;
      vv += d * d;
    }
    vv += __shfl_xor(vv, 16); vv += __shfl_xor(vv, 32);
    float inv = rsqrtf(vv * (1.f / DIN) + 1e-5f);
    bf16x8 av;
#pragma unroll
    for (int j = 0; j < 8; j++)
      av[j] = (__bf16)((xv[j] - mu) * inv * gk[j] + bk[j]);   // gk=bk=0 on pad -> 0
    afrag[t] = av;
  }

  // ---- mm1 tile 0: MFMA + gelu -> h rows [w*32 .. w*32+15] ----
  __bf16* hbb = (__bf16*)smem;                // block h [128][HSTR]
  const int hrow0 = w * 32;
  const f32x4 zf = {0.f, 0.f, 0.f, 0.f};
  {
    f32x4 acc[8];
#pragma unroll
    for (int nt = 0; nt < 8; nt++)
      acc[nt] = __builtin_amdgcn_mfma_f32_16x16x32_bf16(afrag[0], wb1[nt], zf, 0, 0, 0);
#pragma unroll
    for (int nt = 0; nt < 8; nt++) {
      float bias = b1v[nt];
      int col = nt * 16 + l15;
#pragma unroll
      for (int r = 0; r < 4; r++) {
        int row = hrow0 + quad * 4 + r;
        hbb[row * HSTR + col] = (__bf16)gelu_exact(acc[nt][r] + bias);
      }
    }
  }

  // ---- mm1 tile 1: MFMA; then issue wb2/b2 preloads (hide L2 latency under gelu) ----
  bf16x8 wb2[2][4];
  float bias2[2];
  {
    f32x4 acc[8];
#pragma unroll
    for (int nt = 0; nt < 8; nt++)
      acc[nt] = __builtin_amdgcn_mfma_f32_16x16x32_bf16(afrag[1], wb1[nt], zf, 0, 0, 0);
#pragma unroll
    for (int ni = 0; ni < 2; ni++) {
#pragma unroll
      for (int ks = 0; ks < 4; ks++)
        wb2[ni][ks] = *(const bf16x8*)(wfb + 8192 + (((w * 2 + ni) * 4) + ks) * 1024 + lane * 16);
      bias2[ni] = b2[(w * 2 + ni) * 16 + l15];
    }
#pragma unroll
    for (int nt = 0; nt < 8; nt++) {
      float bias = b1v[nt];
      int col = nt * 16 + l15;
#pragma unroll
      for (int r = 0; r < 4; r++) {
        int row = hrow0 + 16 + quad * 4 + r;
        hbb[row * HSTR + col] = (__bf16)gelu_exact(acc[nt][r] + bias);
      }
    }
  }

  __syncthreads();   // h ready block-wide (the only barrier)

  // ---- mm2: out = h @ w2 + b2. Wave w owns col-tiles {2w,2w+1}; w2 in regs ----
  const long long orow0 = (long long)blockIdx.x * MTILE;
  const int c0 = (w * 2 + 0) * 16 + l15;
  const int c1 = (w * 2 + 1) * 16 + l15;
#pragma unroll
  for (int mt = 0; mt < 8; mt++) {
    bf16x8 af[4];
#pragma unroll
    for (int ks = 0; ks < 4; ks++)
      af[ks] = *(const bf16x8*)((const unsigned char*)smem +
                 (mt * 16 + l15) * (HSTR * 2) + ks * 64 + quad * 16);
    f32x4 a0 = zf, a1 = zf;
#pragma unroll
    for (int ks = 0; ks < 4; ks++) {
      a0 = __builtin_amdgcn_mfma_f32_16x16x32_bf16(af[ks], wb2[0][ks], a0, 0, 0, 0);
      a1 = __builtin_amdgcn_mfma_f32_16x16x32_bf16(af[ks], wb2[1][ks], a1, 0, 0, 0);
    }
    float* orow = out + (orow0 + mt * 16) * DP;
#pragma unroll
    for (int r = 0; r < 4; r++) {
      int row = quad * 4 + r;
      orow[row * DP + c0] = a0[r] + bias2[0];
      orow[row * DP + c1] = a1[r] + bias2[1];
    }
  }
}

extern "C" void kernel_launch(void* const* d_in, const int* in_sizes, int n_in,
                              void* d_out, int out_size, void* d_ws, size_t ws_size,
                              hipStream_t stream) {
  const float* x   = (const float*)d_in[0];
  const float* gam = (const float*)d_in[1];
  const float* bet = (const float*)d_in[2];
  const float* w1  = (const float*)d_in[3];
  const float* b1  = (const float*)d_in[4];
  const float* w2  = (const float*)d_in[5];
  const float* b2  = (const float*)d_in[6];
  float* out = (float*)d_out;
  unsigned short* wf = (unsigned short*)d_ws;   // 40KB of packed bf16 weight frags

  prep_kernel<<<80, 256, 0, stream>>>(w1, w2, wf);
  fused_kernel<<<NBLK, 256, 0, stream>>>(x, gam, bet, b1, b2, wf, out);
}

// Round 4
// 328.026 us; speedup vs baseline: 1.1095x; 1.0519x over previous
//
#include <hip/hip_runtime.h>
#include <hip/hip_bf16.h>
#include <stdint.h>

// Problem constants
#define BT    (256*2048)      // 524288 tokens
#define DIN   25
#define DP    128
#define MTILE 128             // tokens per block (4 waves x 32 tokens)
#define NBLK  (BT/MTILE)      // 4096 blocks
#define BAND  8192            // per-wave h band: 32 rows x 128 cols x 2B (swizzled)
#define XOFF  4992            // x stage inside band (3200B = 200x16B); tile-0 h writes
                              // end at byte 4095 -> disjoint; tile-1 writes fenced
#define SM_BYTES (4*BAND)     // 32768 B

typedef __attribute__((ext_vector_type(8))) __bf16 bf16x8;
typedef __attribute__((ext_vector_type(4))) __bf16 bf16x4;
typedef __attribute__((ext_vector_type(4))) float  f32x4;
typedef __attribute__((ext_vector_type(2))) float  f32x2;

__device__ __forceinline__ unsigned short f2bf(float f) {
  unsigned int u = __float_as_uint(f);
  u += 0x7fffu + ((u >> 16) & 1u);          // round-to-nearest-even
  return (unsigned short)(u >> 16);
}

// exact-erf GELU via Abramowitz&Stegun 7.1.26 (|eps|<=1.5e-7), ~15 VALU ops
__device__ __forceinline__ float gelu_exact(float x) {
  float z  = 0.70710678118654752f * x;
  float az = __builtin_fabsf(z);
  float t  = __builtin_amdgcn_rcpf(1.0f + 0.3275911f * az);
  float p  = t*(0.254829592f + t*(-0.284496736f + t*(1.421413741f +
             t*(-1.453152027f + t*1.061405429f))));
  float e  = __expf(-z*z);                  // v_exp_f32 path
  float erf_az = 1.0f - p*e;
  float erf_z  = (x < 0.f) ? -erf_az : erf_az;
  return 0.5f * x * (1.0f + erf_z);
}

__device__ __forceinline__ void async16(void* lds, const void* g) {
  __builtin_amdgcn_global_load_lds(
      (const __attribute__((address_space(1))) unsigned int*)g,
      (__attribute__((address_space(3)))       unsigned int*)lds, 16, 0, 0);
}

// ---------------------------------------------------------------------------
// Prep: pack w1/w2 into bf16 MFMA B-frags with COLUMN-PERMUTED lane ownership.
// B-frag (16x16x32): elem(lane,j) sits at (k=(lane>>4)*8+j, frag-n=lane&15).
//  w1 frag f (0..7):  frag-n l -> true col n1 = (f>>2)*64 + l*4 + (f&3)
//     => lane l15 owns 4 ADJACENT h cols {4*l15..+3} per 64-col group -> b64 h writes
//  w2 frag F (0..7):  frag-n l -> true col n2 = (F>>1)*32 + l*2 + (F&1)
//     => lane l15 owns 2 ADJACENT out cols -> dwordx2 out stores
// Layout: wf[0..8KB) = w1 frags f*1KB ; wf[8KB + (F*4+ks)*1KB) = w2 (ks = K/32)
// ---------------------------------------------------------------------------
__global__ void prep_kernel(const float* __restrict__ w1, const float* __restrict__ w2,
                            unsigned short* __restrict__ wf) {
  int idx = blockIdx.x * 256 + threadIdx.x;
  if (idx >= 40 * 512) return;
  int f = idx >> 9, r = idx & 511, l = r >> 3, j = r & 7;
  int l15 = l & 15, kq = (l >> 4) * 8 + j;
  float val;
  if (f < 8) {                       // w1 frag f
    int n = (f >> 2) * 64 + l15 * 4 + (f & 3);
    val = (kq < DIN) ? w1[kq * DP + n] : 0.f;
  } else {                           // w2 frag: q = F*4 + ks
    int q = f - 8, F = q >> 2, ks = q & 3;
    int k = ks * 32 + kq;
    int n = (F >> 1) * 32 + l15 * 2 + (F & 1);
    val = w2[k * DP + n];
  }
  wf[idx] = f2bf(val);
}

// ---------------------------------------------------------------------------
// Fused LN -> mm1(+b1,GELU) -> mm2(+b2). ONE block barrier.
// Per wave: exact x stage (200x16B async to own band) -> fused LN (shfl) ->
// mm1 in 2 col-groups of 4 frags (low acc liveness) -> b64 h writes into
// XOR-swizzled [32][128] band -> issue wb2 preload -> barrier -> mm2
// col-split (wb2 in regs, b128 af reads) -> dwordx2 out stores.
// ---------------------------------------------------------------------------
__global__ __launch_bounds__(256, 3) void fused_kernel(
    const float* __restrict__ x,   const float* __restrict__ gam,
    const float* __restrict__ bet, const float* __restrict__ b1,
    const float* __restrict__ b2,  const unsigned short* __restrict__ wfr,
    float* __restrict__ out) {
  __shared__ __align__(16) unsigned char smem[SM_BYTES];
  const int tid  = threadIdx.x;
  const int lane = tid & 63, w = tid >> 6;
  const int quad = lane >> 4, l15 = lane & 15;
  const int kbase = quad * 8;
  const long long rowW = (long long)blockIdx.x * MTILE + w * 32;  // wave's first token
  unsigned char* band = smem + w * BAND;
  const unsigned char* wfb = (const unsigned char*)wfr;

  // ---- stage this wave's 32 rows of x (exactly 3200 B = 200 chunks) ----
  {
    const unsigned char* src = (const unsigned char*)x + rowW * (DIN * 4);
    for (int c = lane; c < 200; c += 64)
      async16(band + XOFF + c * 16, src + c * 16);
  }

  // ---- per-lane small preloads + w1 frags (overlap the HBM x fetch) ----
  float gk[8], bk[8];
#pragma unroll
  for (int j = 0; j < 8; j++) {
    int k = kbase + j;
    bool v = (k < DIN);
    gk[j] = v ? gam[k] : 0.f;
    bk[j] = v ? bet[k] : 0.f;
  }
  bf16x8 wb1[8];
#pragma unroll
  for (int f = 0; f < 8; f++)
    wb1[f] = *(const bf16x8*)(wfb + f * 1024 + lane * 16);
  float b1v[8];                                   // bias at true col n1(f,l15)
#pragma unroll
  for (int f = 0; f < 8; f++)
    b1v[f] = b1[(f >> 2) * 64 + l15 * 4 + (f & 3)];

  // wait for this wave's global_load_lds (wave-local; no block barrier)
  asm volatile("s_waitcnt vmcnt(0)" ::: "memory");
  __builtin_amdgcn_sched_barrier(0);

  // ---- LN fused into A-frag build (two-pass variance, registers + shfl) ----
  const float* xs = (const float*)(band + XOFF);
  bf16x8 afrag[2];
#pragma unroll
  for (int t = 0; t < 2; t++) {
    float xv[8];
    float s = 0.f;
#pragma unroll
    for (int j = 0; j < 8; j++) {
      int k = kbase + j;
      float v = 0.f;
      if (k < DIN) v = xs[(t * 16 + l15) * DIN + k];
      xv[j] = v;
      s += v;
    }
    s += __shfl_xor(s, 16);  s += __shfl_xor(s, 32);
    float mu = s * (1.f / DIN);
    float vv = 0.f;
#pragma unroll
    for (int j = 0; j < 8; j++) {
      int k = kbase + j;
      float d = (k < DIN) ? (xv[j] - mu) : 0.f;
      vv += d * d;
    }
    vv += __shfl_xor(vv, 16); vv += __shfl_xor(vv, 32);
    float inv = rsqrtf(vv * (1.f / DIN) + 1e-5f);
    bf16x8 av;
#pragma unroll
    for (int j = 0; j < 8; j++)
      av[j] = (__bf16)((xv[j] - mu) * inv * gk[j] + bk[j]);   // gk=bk=0 on pad
    afrag[t] = av;
  }
  // x ds_reads must complete before h ds_writes overwrite the stage region
  asm volatile("s_waitcnt lgkmcnt(0)" ::: "memory");
  __builtin_amdgcn_sched_barrier(0);

  // ---- mm1: 2 tiles x 2 col-groups of 4 frags; b64 swizzled h writes ----
  const f32x4 zf = {0.f, 0.f, 0.f, 0.f};
#pragma unroll
  for (int t = 0; t < 2; t++) {
#pragma unroll
    for (int g = 0; g < 2; g++) {
      f32x4 acc[4];
#pragma unroll
      for (int c = 0; c < 4; c++)
        acc[c] = __builtin_amdgcn_mfma_f32_16x16x32_bf16(afrag[t], wb1[g * 4 + c], zf, 0, 0, 0);
#pragma unroll
      for (int r = 0; r < 4; r++) {
        int rl   = t * 16 + quad * 4 + r;          // row within band (0..31)
        int swz  = ((quad * 4 + r) & 7) << 4;      // rl&7 == (quad*4+r)&7
        bf16x4 hv;
#pragma unroll
        for (int c = 0; c < 4; c++)
          hv[c] = (__bf16)gelu_exact(acc[c][r] + b1v[g * 4 + c]);
        *(bf16x4*)(band + rl * 256 + ((g * 128 + l15 * 8) ^ swz)) = hv;
      }
    }
  }

  // ---- wb2/b2 preload (covered by epilogue + barrier wait; 32 regs live) ----
  bf16x8 wb2[2][4];
#pragma unroll
  for (int ni = 0; ni < 2; ni++)
#pragma unroll
    for (int ks = 0; ks < 4; ks++)
      wb2[ni][ks] = *(const bf16x8*)(wfb + 8192 + (((w * 2 + ni) * 4) + ks) * 1024 + lane * 16);
  f32x2 bias2 = *(const f32x2*)(b2 + w * 32 + 2 * l15);

  __syncthreads();   // h ready block-wide (the only barrier)

  // ---- mm2: out = h @ w2 + b2. Wave w owns out cols [w*32, w*32+32) ----
  const long long orow0 = (long long)blockIdx.x * MTILE;
  const int rswz = (l15 & 7) << 4;                 // row = mt*16+l15 -> row&7 = l15&7
#pragma unroll
  for (int mt = 0; mt < 8; mt++) {
    bf16x8 af[4];
#pragma unroll
    for (int ks = 0; ks < 4; ks++)
      af[ks] = *(const bf16x8*)(smem + (mt * 16 + l15) * 256 + ((ks * 64 + quad * 16) ^ rswz));
    f32x4 a0 = zf, a1 = zf;
#pragma unroll
    for (int ks = 0; ks < 4; ks++) {
      a0 = __builtin_amdgcn_mfma_f32_16x16x32_bf16(af[ks], wb2[0][ks], a0, 0, 0, 0);
      a1 = __builtin_amdgcn_mfma_f32_16x16x32_bf16(af[ks], wb2[1][ks], a1, 0, 0, 0);
    }
    float* orow = out + (orow0 + mt * 16) * DP + w * 32 + 2 * l15;
#pragma unroll
    for (int r = 0; r < 4; r++) {
      int row = quad * 4 + r;
      f32x2 o; o[0] = a0[r] + bias2[0]; o[1] = a1[r] + bias2[1];
      *(f32x2*)(orow + row * DP) = o;              // adjacent cols: dwordx2
    }
  }
}

extern "C" void kernel_launch(void* const* d_in, const int* in_sizes, int n_in,
                              void* d_out, int out_size, void* d_ws, size_t ws_size,
                              hipStream_t stream) {
  const float* x   = (const float*)d_in[0];
  const float* gam = (const float*)d_in[1];
  const float* bet = (const float*)d_in[2];
  const float* w1  = (const float*)d_in[3];
  const float* b1  = (const float*)d_in[4];
  const float* w2  = (const float*)d_in[5];
  const float* b2  = (const float*)d_in[6];
  float* out = (float*)d_out;
  unsigned short* wf = (unsigned short*)d_ws;   // 40KB of packed bf16 weight frags

  prep_kernel<<<80, 256, 0, stream>>>(w1, w2, wf);
  fused_kernel<<<NBLK, 256, 0, stream>>>(x, gam, bet, b1, b2, wf, out);
}